// Round 10
// baseline (3516.286 us; speedup 1.0000x reference)
//
#include <hip/hip_runtime.h>
#include <stdint.h>

typedef float f32x4 __attribute__((ext_vector_type(4)));
typedef short s16x8 __attribute__((ext_vector_type(8)));
typedef short s16x4 __attribute__((ext_vector_type(4)));
typedef uint32_t u32x4 __attribute__((ext_vector_type(4)));

#define HDIM 128
#define TLEN 512
#define BT 16
#define SPIN_LIMIT (1 << 22)   // watchdog: bounded spin, ~100ms worst case

__device__ __forceinline__ unsigned short f2bf(float f) {
    union { float f; uint32_t u; } v; v.f = f;
    uint32_t r = v.u + 0x7FFFu + ((v.u >> 16) & 1u);
    return (unsigned short)(r >> 16);
}
__device__ __forceinline__ float bfhi(uint32_t u){ union{uint32_t u;float f;}v; v.u = u & 0xFFFF0000u; return v.f; }
__device__ __forceinline__ float bflo(uint32_t u){ union{uint32_t u;float f;}v; v.u = u << 16; return v.f; }
__device__ __forceinline__ float bf2f(short s){ union{uint32_t u;float f;}v; v.u = ((uint32_t)(unsigned short)s) << 16; return v.f; }

__device__ __forceinline__ float sigmoidf_(float x){
    float e = __expf(-x);
    return __builtin_amdgcn_rcpf(1.0f + e);
}
__device__ __forceinline__ float tanhf_(float x){
    float e = __expf(2.0f * x);
    return 1.0f - 2.0f * __builtin_amdgcn_rcpf(1.0f + e);
}

#define MFMA16(A, B, C) __builtin_amdgcn_mfma_f32_16x16x32_bf16((A), (B), (C), 0, 0, 0)
#define UNPK(arr, idx) (((idx) & 1) ? bfhi(arr[(idx) >> 1]) : bflo(arr[(idx) >> 1]))

// ============================================================================
// Pipelined 2-block-per-pair kernel with depth-limited backpressured ring.
// even blocks = layer 0 (producer), odd = layer 1 + head (consumer).
// Chunk = 8 steps. Producer may lead by at most D chunks.
// All spins are BOUNDED (watchdog) so the kernel always terminates.
// ============================================================================
__global__ __launch_bounds__(512, 2) void lstm_pipe_kernel(
    const float* __restrict__ x,
    const float* __restrict__ Wih0,
    const float* __restrict__ Whh0,
    const float* __restrict__ bih0,
    const float* __restrict__ bhh0,
    const float* __restrict__ Wih1,
    const float* __restrict__ Whh1,
    const float* __restrict__ bih1,
    const float* __restrict__ bhh1,
    const float* __restrict__ W1,
    const float* __restrict__ b1,
    const float* __restrict__ W2,
    const float* __restrict__ b2,
    short* __restrict__ ring,        // [128 pairs][8*D steps][2048 shorts]
    int* __restrict__ prodF,         // [128] stride-16 chunk counters (producer)
    int* __restrict__ consF,         // [128] stride-16 chunk counters (consumer)
    float* __restrict__ out,
    const int dchunks,               // ring depth in chunks
    const int dmask)                 // (8*dchunks - 1)
{
    __shared__ __align__(16) short h0A[2][2048];       // A: h0 ping-pong frags
    __shared__ __align__(16) short h1f[2][2048];       // B: h1 ping-pong frags
    __shared__ __align__(16) float headH[16 * HDIM];   // B: final h1 f32
    __shared__ __align__(16) float headL[16 * 64];     // B: relu layer

    const int role = blockIdx.x & 1;     // 0 = layer0, 1 = layer1+head
    const int p    = blockIdx.x >> 1;    // pair index = batch group
    const int tid  = threadIdx.x;
    const int w = tid >> 6;              // wave 0..7, owns units [16w,16w+16)
    const int l = tid & 63;
    const int n = l & 15;                // batch col
    const int q = l >> 4;                // k-group / row-quad
    const int b0 = p * BT;
    const float* xrow = x + (size_t)(b0 + n) * TLEN;
    short* ringp = ring + (size_t)p * (size_t)(dmask + 1) * 2048;

    // B-fragment slot for this lane's 4 units
    const int u0 = w * 16 + q * 4;
    const int fragoff = (((u0 >> 5) * 64) + n + 16 * ((u0 >> 3) & 3)) * 8 + (u0 & 7);

    if (role == 0) {
        // ================= A: layer 0 producer =================
        s16x8 w0f[4][4];
        #pragma unroll
        for (int c = 0; c < 4; ++c) {
            #pragma unroll
            for (int tile = 0; tile < 4; ++tile) {
                const int g  = tile * 128 + w * 16 + n;
                const int k0 = c * 32 + q * 8;
                const float* pw = Whh0 + g * HDIM + k0;
                s16x8 a;
                #pragma unroll
                for (int j = 0; j < 8; ++j) a[j] = (short)f2bf(pw[j]);
                w0f[c][tile] = a;
            }
        }
        uint32_t b0p[8], wxp[8];
        #pragma unroll
        for (int i = 0; i < 8; ++i) {
            const int tr0 = 2 * i;
            const int tile = tr0 >> 2, r0 = tr0 & 3;
            const int g0 = tile * 128 + u0 + r0;
            const int g1 = g0 + 1;
            b0p[i] = ((uint32_t)f2bf(bih0[g1] + bhh0[g1]) << 16) | f2bf(bih0[g0] + bhh0[g0]);
            wxp[i] = ((uint32_t)f2bf(Wih0[g1]) << 16) | f2bf(Wih0[g0]);
        }
        float c0v[4] = {0.f, 0.f, 0.f, 0.f};

        // prologue: h0[0] = pointwise(b0 + wx*x[0])   (chunk 0, no wait)
        {
            const float x0 = xrow[0];
            s16x4 hw;
            #pragma unroll
            for (int r = 0; r < 4; ++r) {
                const float pi = fmaf(UNPK(wxp, r),      x0, UNPK(b0p, r));
                const float pg = fmaf(UNPK(wxp, 8 + r),  x0, UNPK(b0p, 8 + r));
                const float po = fmaf(UNPK(wxp, 12 + r), x0, UNPK(b0p, 12 + r));
                const float ig = sigmoidf_(pi);
                const float gg = tanhf_(pg);
                const float og = sigmoidf_(po);
                const float cc = ig * gg;           // f*c(-1) = 0
                c0v[r] = cc;
                hw[r] = (short)f2bf(og * tanhf_(cc));
            }
            *(s16x4*)&h0A[0][fragoff] = hw;
            *(s16x4*)&ringp[fragoff] = hw;          // slot 0
        }
        __syncthreads();

        #pragma unroll 1
        for (int i = 0; i < 511; ++i) {
            // backpressure (bounded): before writing first step of chunk c,
            // need consumer done with chunk c-dchunks: consF >= c+1-dchunks
            if (((i + 1) & 7) == 0) {
                const int c = (i + 1) >> 3;
                const int needCons = c + 1 - dchunks;
                if (needCons > 0) {
                    if (tid == 0) {
                        int guard = 0;
                        while (__hip_atomic_load(&consF[p * 16], __ATOMIC_ACQUIRE,
                                                 __HIP_MEMORY_SCOPE_AGENT) < needCons) {
                            if (++guard > SPIN_LIMIT) break;   // watchdog
                            __builtin_amdgcn_s_sleep(2);
                        }
                    }
                    __syncthreads();
                }
            }
            const short* R = h0A[i & 1];
            short*       W = h0A[(i + 1) & 1];
            const float xv = xrow[i + 1];
            s16x8 hb[4];
            #pragma unroll
            for (int c = 0; c < 4; ++c) hb[c] = *(const s16x8*)&R[(c * 64 + l) * 8];
            f32x4 a[4];
            #pragma unroll
            for (int tile = 0; tile < 4; ++tile) {
                #pragma unroll
                for (int r = 0; r < 4; ++r) {
                    const int tr = tile * 4 + r;
                    a[tile][r] = fmaf(UNPK(wxp, tr), xv, UNPK(b0p, tr));
                }
            }
            #pragma unroll
            for (int c = 0; c < 4; ++c) {
                #pragma unroll
                for (int tile = 0; tile < 4; ++tile)
                    a[tile] = MFMA16(w0f[c][tile], hb[c], a[tile]);
            }
            s16x4 hw;
            #pragma unroll
            for (int r = 0; r < 4; ++r) {
                const float ig = sigmoidf_(a[0][r]);
                const float fg = sigmoidf_(a[1][r]);
                const float gg = tanhf_(a[2][r]);
                const float og = sigmoidf_(a[3][r]);
                const float cc = fmaf(fg, c0v[r], ig * gg);
                c0v[r] = cc;
                hw[r] = (short)f2bf(og * tanhf_(cc));
            }
            *(s16x4*)&W[fragoff] = hw;
            *(s16x4*)&ringp[(size_t)((i + 1) & dmask) * 2048 + fragoff] = hw;

            if (((i + 2) & 7) == 0) {
                __threadfence();                 // make ring stores agent-visible
                __syncthreads();
                if (tid == 0)
                    __hip_atomic_store(&prodF[p * 16], (i + 2) >> 3,
                                       __ATOMIC_RELEASE, __HIP_MEMORY_SCOPE_AGENT);
            } else {
                __syncthreads();
            }
        }
        return;   // A blocks write no output
    }

    // ================= B: layer 1 consumer + head =================
    s16x8 wi1f[4][4], wh1f[4][4];
    #pragma unroll
    for (int c = 0; c < 4; ++c) {
        #pragma unroll
        for (int tile = 0; tile < 4; ++tile) {
            const int g  = tile * 128 + w * 16 + n;
            const int k0 = c * 32 + q * 8;
            const float* p1 = Wih1 + g * HDIM + k0;
            const float* p2 = Whh1 + g * HDIM + k0;
            s16x8 a, b;
            #pragma unroll
            for (int j = 0; j < 8; ++j) { a[j] = (short)f2bf(p1[j]); b[j] = (short)f2bf(p2[j]); }
            wi1f[c][tile] = a; wh1f[c][tile] = b;
        }
    }
    uint32_t b1p[8];
    #pragma unroll
    for (int i = 0; i < 8; ++i) {
        const int tr0 = 2 * i;
        const int tile = tr0 >> 2, r0 = tr0 & 3;
        const int g0 = tile * 128 + u0 + r0;
        const int g1 = g0 + 1;
        b1p[i] = ((uint32_t)f2bf(bih1[g1] + bhh1[g1]) << 16) | f2bf(bih1[g0] + bhh1[g0]);
    }
    // zero h1[-1] (read slot for k=0 is h1f[1])
    for (int s2 = tid; s2 < 1024; s2 += 512) ((uint32_t*)h1f[1])[s2] = 0u;
    float c1v[4] = {0.f, 0.f, 0.f, 0.f};

#define WAITCHUNK(C) do {                                                     \
    if (tid == 0) {                                                           \
        int guard = 0;                                                        \
        while (__hip_atomic_load(&prodF[p * 16], __ATOMIC_ACQUIRE,            \
                                 __HIP_MEMORY_SCOPE_AGENT) < (C)) {           \
            if (++guard > SPIN_LIMIT) break;   /* watchdog */                 \
            __builtin_amdgcn_s_sleep(2);                                      \
        }                                                                     \
    }                                                                         \
    __syncthreads();                                                          \
    __threadfence();  /* acquire: see producer's ring stores */               \
} while (0)

#define POSTCHUNK(C) do {                                                     \
    if (tid == 0)                                                             \
        __hip_atomic_store(&consF[p * 16], (C),                               \
                           __ATOMIC_RELEASE, __HIP_MEMORY_SCOPE_AGENT);       \
} while (0)

#define LOADCUR(DST, T) do {                                                  \
    _Pragma("unroll")                                                         \
    for (int c = 0; c < 4; ++c)                                               \
        (DST)[c] = *(const s16x8*)&ringp[(size_t)((T) & dmask) * 2048 + (c * 64 + l) * 8]; \
} while (0)

#define BSTEP(K, CUR, NXT, DO_PF) do {                                        \
    const short* R1_ = h1f[((K) + 1) & 1];                                    \
    short*       W1_ = h1f[(K) & 1];                                          \
    s16x8 hb1_[4];                                                            \
    _Pragma("unroll")                                                         \
    for (int c = 0; c < 4; ++c) hb1_[c] = *(const s16x8*)&R1_[(c * 64 + l) * 8]; \
    f32x4 a_[4];                                                              \
    _Pragma("unroll")                                                         \
    for (int tile = 0; tile < 4; ++tile) {                                    \
        _Pragma("unroll")                                                     \
        for (int r = 0; r < 4; ++r) a_[tile][r] = UNPK(b1p, tile * 4 + r);    \
    }                                                                         \
    _Pragma("unroll")                                                         \
    for (int c = 0; c < 4; ++c) {                                             \
        _Pragma("unroll")                                                     \
        for (int tile = 0; tile < 4; ++tile)                                  \
            a_[tile] = MFMA16(wi1f[c][tile], (CUR)[c], a_[tile]);             \
    }                                                                         \
    if (DO_PF) { LOADCUR(NXT, (K) + 1); }                                     \
    _Pragma("unroll")                                                         \
    for (int c = 0; c < 4; ++c) {                                             \
        _Pragma("unroll")                                                     \
        for (int tile = 0; tile < 4; ++tile)                                  \
            a_[tile] = MFMA16(wh1f[c][tile], hb1_[c], a_[tile]);              \
    }                                                                         \
    s16x4 hw_;                                                                \
    _Pragma("unroll")                                                         \
    for (int r = 0; r < 4; ++r) {                                             \
        const float ig = sigmoidf_(a_[0][r]);                                 \
        const float fg = sigmoidf_(a_[1][r]);                                 \
        const float gg = tanhf_(a_[2][r]);                                    \
        const float og = sigmoidf_(a_[3][r]);                                 \
        const float cc = fmaf(fg, c1v[r], ig * gg);                           \
        c1v[r] = cc;                                                          \
        hw_[r] = (short)f2bf(og * tanhf_(cc));                                \
    }                                                                         \
    *(s16x4*)&W1_[fragoff] = hw_;                                             \
    __syncthreads();                                                          \
} while (0)

    s16x8 curA[4], curB[4];

    #pragma unroll 1
    for (int c64 = 0; c64 < 63; ++c64) {
        WAITCHUNK(c64 + 1);
        const int kb = 8 * c64;
        LOADCUR(curA, kb);
        BSTEP(kb + 0, curA, curB, true);
        BSTEP(kb + 1, curB, curA, true);
        BSTEP(kb + 2, curA, curB, true);
        BSTEP(kb + 3, curB, curA, true);
        BSTEP(kb + 4, curA, curB, true);
        BSTEP(kb + 5, curB, curA, true);
        BSTEP(kb + 6, curA, curB, true);
        BSTEP(kb + 7, curB, curA, false);
        POSTCHUNK(c64 + 1);            // chunk-c ring reads retired (barrier above)
    }
    // final chunk: k = 504..510, then epilogue k = 511
    WAITCHUNK(64);
    LOADCUR(curA, 504);
    BSTEP(504, curA, curB, true);
    BSTEP(505, curB, curA, true);
    BSTEP(506, curA, curB, true);
    BSTEP(507, curB, curA, true);
    BSTEP(508, curA, curB, true);
    BSTEP(509, curB, curA, true);
    BSTEP(510, curA, curB, true);      // prefetches curB = h0[511]

    // epilogue t=511: gates1 only; final h1 -> headH (f32)
    {
        const short* R1 = h1f[0];      // h1[510]
        s16x8 hb1_[4];
        #pragma unroll
        for (int c = 0; c < 4; ++c) hb1_[c] = *(const s16x8*)&R1[(c * 64 + l) * 8];
        f32x4 a_[4];
        #pragma unroll
        for (int tile = 0; tile < 4; ++tile) {
            #pragma unroll
            for (int r = 0; r < 4; ++r) a_[tile][r] = UNPK(b1p, tile * 4 + r);
        }
        #pragma unroll
        for (int c = 0; c < 4; ++c) {
            #pragma unroll
            for (int tile = 0; tile < 4; ++tile) {
                a_[tile] = MFMA16(wi1f[c][tile], curB[c], a_[tile]);
                a_[tile] = MFMA16(wh1f[c][tile], hb1_[c], a_[tile]);
            }
        }
        f32x4 hv;
        #pragma unroll
        for (int r = 0; r < 4; ++r) {
            const float ig = sigmoidf_(a_[0][r]);
            const float fg = sigmoidf_(a_[1][r]);
            const float gg = tanhf_(a_[2][r]);
            const float og = sigmoidf_(a_[3][r]);
            const float cc = fmaf(fg, c1v[r], ig * gg);
            hv[r] = og * tanhf_(cc);
        }
        *(f32x4*)&headH[n * HDIM + u0] = hv;
    }
    __syncthreads();

    #pragma unroll
    for (int rep = 0; rep < 2; ++rep) {
        const int idx = tid + rep * 512;     // 1024 = 16 batch * 64 hidden
        const int nn = idx >> 6, j = idx & 63;
        float s = b1[j];
        const float* wrow = W1 + j * HDIM;
        const float* hrow = headH + nn * HDIM;
        #pragma unroll
        for (int k = 0; k < HDIM; k += 4) {
            const f32x4 hv = *(const f32x4*)&hrow[k];
            const f32x4 wv = *(const f32x4*)&wrow[k];
            s += hv[0]*wv[0] + hv[1]*wv[1] + hv[2]*wv[2] + hv[3]*wv[3];
        }
        headL[nn * 64 + j] = fmaxf(s, 0.0f);
    }
    __syncthreads();

    if (tid < 128) {
        const int nn = tid >> 3, cls = tid & 7;
        float s = b2[cls];
        const float* wrow = W2 + cls * 64;
        const float* hrow = headL + nn * 64;
        #pragma unroll
        for (int k = 0; k < 64; k += 4) {
            const f32x4 hv = *(const f32x4*)&hrow[k];
            const f32x4 wv = *(const f32x4*)&wrow[k];
            s += hv[0]*wv[0] + hv[1]*wv[1] + hv[2]*wv[2] + hv[3]*wv[3];
        }
        out[(size_t)(b0 + nn) * 8 + cls] = s;
    }
#undef WAITCHUNK
#undef POSTCHUNK
#undef LOADCUR
#undef BSTEP
}

// ============================================================================
// Fallback (round-6 kernel, 954 us): used when ws_size is too small.
// ============================================================================
__global__ __launch_bounds__(512, 2) void lstm_fused_kernel(
    const float* __restrict__ x,
    const float* __restrict__ Wih0,
    const float* __restrict__ Whh0,
    const float* __restrict__ bih0,
    const float* __restrict__ bhh0,
    const float* __restrict__ Wih1,
    const float* __restrict__ Whh1,
    const float* __restrict__ bih1,
    const float* __restrict__ bhh1,
    const float* __restrict__ W1,
    const float* __restrict__ b1,
    const float* __restrict__ W2,
    const float* __restrict__ b2,
    float* __restrict__ out)
{
    __shared__ __align__(16) short wh1lds[65536];
    __shared__ __align__(16) short h0f0[2048], h0f1[2048];
    __shared__ __align__(16) short h1f0[2048], h1f1[2048];
    __shared__ __align__(16) float b1lds[4][8][16];

    const int tid = threadIdx.x;
    const int w   = tid >> 6;
    const int wl  = w & 3;
    const bool isL0 = (w < 4);
    const int l = tid & 63;
    const int n = l & 15;
    const int q = l >> 4;
    const int b0 = blockIdx.x * BT;
    const float* xrow = x + (size_t)(b0 + n) * TLEN;

    for (int s2 = tid; s2 < 8192; s2 += 512) {
        const int ll = s2 & 63, t2 = (s2 >> 6) & 7, cc = (s2 >> 9) & 3, wv = s2 >> 11;
        const int row = (t2 >> 1) * 128 + 32 * wv + 16 * (t2 & 1) + (ll & 15);
        const int k0  = cc * 32 + (ll >> 4) * 8;
        const float* p = Whh1 + row * HDIM + k0;
        s16x8 a;
        #pragma unroll
        for (int j = 0; j < 8; ++j) a[j] = (short)f2bf(p[j]);
        *(s16x8*)&wh1lds[s2 * 8] = a;
    }
    {
        const int idx = tid;
        const int wv = idx >> 7, t2 = (idx >> 4) & 7, j = idx & 15;
        const int row = (t2 >> 1) * 128 + 32 * wv + 16 * (t2 & 1) + j;
        b1lds[wv][t2][j] = bih1[row] + bhh1[row];
    }
    for (int s2 = tid; s2 < 1024; s2 += 512) ((uint32_t*)h1f1)[s2] = 0u;

    const int ub0 = 32 * wl + 4 * q;
    const int ub1 = ub0 + 16;
    const int fo0 = ((ub0 >> 5) * 64 + n + 16 * ((ub0 >> 3) & 3)) * 8 + (ub0 & 7);
    const int fo1 = ((ub1 >> 5) * 64 + n + 16 * ((ub1 >> 3) & 3)) * 8 + (ub1 & 7);

#define L0ITER(K, R0, W0) do {                                                \
    const int xi_ = (K) + 1;                                                  \
    const float xv_ = xrow[xi_ < TLEN ? xi_ : (TLEN - 1)];                    \
    s16x8 hb_[4];                                                             \
    _Pragma("unroll")                                                         \
    for (int c = 0; c < 4; ++c) hb_[c] = *(const s16x8*)&(R0)[(c * 64 + l) * 8]; \
    f32x4 a_[8];                                                              \
    _Pragma("unroll")                                                         \
    for (int t2 = 0; t2 < 8; ++t2) {                                          \
        _Pragma("unroll")                                                     \
        for (int r = 0; r < 4; ++r)                                           \
            a_[t2][r] = fmaf(bfhi(bwx[t2][r]), xv_, bflo(bwx[t2][r]));        \
    }                                                                         \
    _Pragma("unroll")                                                         \
    for (int c = 0; c < 4; ++c) {                                             \
        _Pragma("unroll")                                                     \
        for (int t2 = 0; t2 < 8; ++t2)                                        \
            a_[t2] = MFMA16(w0f[c][t2], hb_[c], a_[t2]);                      \
    }                                                                         \
    _Pragma("unroll")                                                         \
    for (int h = 0; h < 2; ++h) {                                             \
        s16x4 hw;                                                             \
        _Pragma("unroll")                                                     \
        for (int r = 0; r < 4; ++r) {                                         \
            const float ig = sigmoidf_(a_[0 + h][r]);                         \
            const float fg = sigmoidf_(a_[2 + h][r]);                         \
            const float gg = tanhf_(a_[4 + h][r]);                            \
            const float og = sigmoidf_(a_[6 + h][r]);                         \
            const float cc = fmaf(fg, c0_[h][r], ig * gg);                    \
            c0_[h][r] = cc;                                                   \
            hw[r] = (short)f2bf(og * tanhf_(cc));                             \
        }                                                                     \
        *(s16x4*)&(W0)[h ? fo1 : fo0] = hw;                                   \
    }                                                                         \
    __syncthreads();                                                          \
} while (0)

#define L1ITER(K, R0, R1, W1) do {                                            \
    s16x8 hb0_[4], hb1_[4];                                                   \
    _Pragma("unroll")                                                         \
    for (int c = 0; c < 4; ++c) {                                             \
        hb0_[c] = *(const s16x8*)&(R0)[(c * 64 + l) * 8];                     \
        hb1_[c] = *(const s16x8*)&(R1)[(c * 64 + l) * 8];                     \
    }                                                                         \
    f32x4 a_[8];                                                              \
    _Pragma("unroll")                                                         \
    for (int t2 = 0; t2 < 8; ++t2)                                            \
        a_[t2] = *(const f32x4*)&b1lds[wl][t2][q * 4];                        \
    _Pragma("unroll")                                                         \
    for (int c = 0; c < 4; ++c) {                                             \
        _Pragma("unroll")                                                     \
        for (int t2 = 0; t2 < 8; ++t2)                                        \
            a_[t2] = MFMA16(wi1f[c][t2], hb0_[c], a_[t2]);                    \
    }                                                                         \
    _Pragma("unroll")                                                         \
    for (int c = 0; c < 4; ++c) {                                             \
        s16x8 wt_[8];                                                         \
        _Pragma("unroll")                                                     \
        for (int t2 = 0; t2 < 8; ++t2)                                        \
            wt_[t2] = *(const s16x8*)&wh1lds[(((wl * 4 + c) * 8 + t2) * 64 + l) * 8]; \
        _Pragma("unroll")                                                     \
        for (int t2 = 0; t2 < 8; ++t2)                                        \
            a_[t2] = MFMA16(wt_[t2], hb1_[c], a_[t2]);                        \
    }                                                                         \
    _Pragma("unroll")                                                         \
    for (int h = 0; h < 2; ++h) {                                             \
        s16x4 hw;                                                             \
        _Pragma("unroll")                                                     \
        for (int r = 0; r < 4; ++r) {                                         \
            const float ig = sigmoidf_(a_[0 + h][r]);                         \
            const float fg = sigmoidf_(a_[2 + h][r]);                         \
            const float gg = tanhf_(a_[4 + h][r]);                            \
            const float og = sigmoidf_(a_[6 + h][r]);                         \
            const float cc = fmaf(fg, c1_[h][r], ig * gg);                    \
            c1_[h][r] = cc;                                                   \
            hw[r] = (short)f2bf(og * tanhf_(cc));                             \
        }                                                                     \
        *(s16x4*)&(W1)[h ? fo1 : fo0] = hw;                                   \
    }                                                                         \
    __syncthreads();                                                          \
} while (0)

    if (isL0) {
        s16x8 w0f[4][8];
        #pragma unroll
        for (int c = 0; c < 4; ++c) {
            #pragma unroll
            for (int t2 = 0; t2 < 8; ++t2) {
                const int row = (t2 >> 1) * 128 + 32 * wl + 16 * (t2 & 1) + n;
                const int k0 = c * 32 + q * 8;
                const float* p = Whh0 + row * HDIM + k0;
                s16x8 a;
                #pragma unroll
                for (int j = 0; j < 8; ++j) a[j] = (short)f2bf(p[j]);
                w0f[c][t2] = a;
            }
        }
        u32x4 bwx[8];
        #pragma unroll
        for (int t2 = 0; t2 < 8; ++t2) {
            #pragma unroll
            for (int r = 0; r < 4; ++r) {
                const int row = (t2 >> 1) * 128 + 32 * wl + 16 * (t2 & 1) + 4 * q + r;
                bwx[t2][r] = ((uint32_t)f2bf(Wih0[row]) << 16) | f2bf(bih0[row] + bhh0[row]);
            }
        }
        float c0_[2][4] = {{0.f,0.f,0.f,0.f},{0.f,0.f,0.f,0.f}};
        {
            const float x0 = xrow[0];
            #pragma unroll
            for (int h = 0; h < 2; ++h) {
                s16x4 hw;
                #pragma unroll
                for (int r = 0; r < 4; ++r) {
                    const float pi = fmaf(bfhi(bwx[0 + h][r]), x0, bflo(bwx[0 + h][r]));
                    const float pg = fmaf(bfhi(bwx[4 + h][r]), x0, bflo(bwx[4 + h][r]));
                    const float po = fmaf(bfhi(bwx[6 + h][r]), x0, bflo(bwx[6 + h][r]));
                    const float ig = sigmoidf_(pi);
                    const float gg = tanhf_(pg);
                    const float og = sigmoidf_(po);
                    const float cc = ig * gg;
                    c0_[h][r] = cc;
                    hw[r] = (short)f2bf(og * tanhf_(cc));
                }
                *(s16x4*)&h0f0[h ? fo1 : fo0] = hw;
            }
        }
        __syncthreads();
        #pragma unroll 1
        for (int k = 0; k < TLEN; k += 2) {
            L0ITER(k,     h0f0, h0f1);
            L0ITER(k + 1, h0f1, h0f0);
        }
    } else {
        s16x8 wi1f[4][8];
        #pragma unroll
        for (int c = 0; c < 4; ++c) {
            #pragma unroll
            for (int t2 = 0; t2 < 8; ++t2) {
                const int row = (t2 >> 1) * 128 + 32 * wl + 16 * (t2 & 1) + n;
                const int k0 = c * 32 + q * 8;
                const float* p = Wih1 + row * HDIM + k0;
                s16x8 a;
                #pragma unroll
                for (int j = 0; j < 8; ++j) a[j] = (short)f2bf(p[j]);
                wi1f[c][t2] = a;
            }
        }
        float c1_[2][4] = {{0.f,0.f,0.f,0.f},{0.f,0.f,0.f,0.f}};
        __syncthreads();
        #pragma unroll 1
        for (int k = 0; k < TLEN; k += 2) {
            L1ITER(k,     h0f0, h1f1, h1f0);
            L1ITER(k + 1, h0f1, h1f0, h1f1);
        }
    }

    __syncthreads();

    float* headH = (float*)wh1lds;
    float* headL = headH + 16 * HDIM;
    if (!isL0) {
        #pragma unroll
        for (int h = 0; h < 2; ++h) {
            const s16x4 hv = *(const s16x4*)&h1f1[h ? fo1 : fo0];
            f32x4 hf;
            #pragma unroll
            for (int r = 0; r < 4; ++r) hf[r] = bf2f(hv[r]);
            *(f32x4*)&headH[n * HDIM + (h ? ub1 : ub0)] = hf;
        }
    }
    __syncthreads();

    #pragma unroll
    for (int rep = 0; rep < 2; ++rep) {
        const int idx = tid + rep * 512;
        const int nn = idx >> 6, j = idx & 63;
        float s = b1[j];
        const float* wrow = W1 + j * HDIM;
        const float* hrow = headH + nn * HDIM;
        #pragma unroll
        for (int k = 0; k < HDIM; k += 4) {
            const f32x4 hv = *(const f32x4*)&hrow[k];
            const f32x4 wv = *(const f32x4*)&wrow[k];
            s += hv[0]*wv[0] + hv[1]*wv[1] + hv[2]*wv[2] + hv[3]*wv[3];
        }
        headL[nn * 64 + j] = fmaxf(s, 0.0f);
    }
    __syncthreads();

    if (tid < 128) {
        const int nn = tid >> 3, cls = tid & 7;
        float s = b2[cls];
        const float* wrow = W2 + cls * 64;
        const float* hrow = headL + nn * 64;
        #pragma unroll
        for (int k = 0; k < 64; k += 4) {
            const f32x4 hv = *(const f32x4*)&hrow[k];
            const f32x4 wv = *(const f32x4*)&wrow[k];
            s += hv[0]*wv[0] + hv[1]*wv[1] + hv[2]*wv[2] + hv[3]*wv[3];
        }
        out[(size_t)(b0 + nn) * 8 + cls] = s;
    }
#undef L0ITER
#undef L1ITER
}

extern "C" void kernel_launch(void* const* d_in, const int* in_sizes, int n_in,
                              void* d_out, int out_size, void* d_ws, size_t ws_size,
                              hipStream_t stream) {
    const float* x    = (const float*)d_in[0];
    const float* Wih0 = (const float*)d_in[1];
    const float* Whh0 = (const float*)d_in[2];
    const float* bih0 = (const float*)d_in[3];
    const float* bhh0 = (const float*)d_in[4];
    const float* Wih1 = (const float*)d_in[5];
    const float* Whh1 = (const float*)d_in[6];
    const float* bih1 = (const float*)d_in[7];
    const float* bhh1 = (const float*)d_in[8];
    const float* W1   = (const float*)d_in[9];
    const float* b1   = (const float*)d_in[10];
    const float* W2   = (const float*)d_in[11];
    const float* b2   = (const float*)d_in[12];
    float* outp = (float*)d_out;

    const size_t FLAGS_BYTES = 32768;
    // ring bytes per pair per chunk = 8 steps * 2048 shorts * 2B = 32 KB
    size_t avail = (ws_size > FLAGS_BYTES) ? (ws_size - FLAGS_BYTES) : 0;
    const size_t maxChunks = avail / ((size_t)128 * 32768);
    int D = 0;
    for (int cand = 64; cand >= 2; cand >>= 1)
        if (maxChunks >= (size_t)cand) { D = cand; break; }

    if (D >= 2) {
        int*   prodF = (int*)d_ws;                       // [128] stride 16
        int*   consF = (int*)d_ws + 4096;                // byte offset 16 KB
        short* ring  = (short*)((char*)d_ws + FLAGS_BYTES);
        hipMemsetAsync(d_ws, 0, FLAGS_BYTES, stream);    // zero flags every launch
        lstm_pipe_kernel<<<256, 512, 0, stream>>>(
            x, Wih0, Whh0, bih0, bhh0, Wih1, Whh1, bih1, bhh1,
            W1, b1, W2, b2, ring, prodF, consF, outp, D, 8 * D - 1);
    } else {
        lstm_fused_kernel<<<128, 512, 0, stream>>>(
            x, Wih0, Whh0, bih0, bhh0, Wih1, Whh1, bih1, bhh1,
            W1, b1, W2, b2, outp);
    }
}

// Round 11
// 891.101 us; speedup vs baseline: 3.9460x; 3.9460x over previous
//
#include <hip/hip_runtime.h>
#include <stdint.h>

typedef float f32x4 __attribute__((ext_vector_type(4)));
typedef short s16x8 __attribute__((ext_vector_type(8)));
typedef short s16x4 __attribute__((ext_vector_type(4)));
typedef uint32_t u32x4 __attribute__((ext_vector_type(4)));

#define HDIM 128
#define TLEN 512
#define BT 16

__device__ __forceinline__ unsigned short f2bf(float f) {
    union { float f; uint32_t u; } v; v.f = f;
    uint32_t r = v.u + 0x7FFFu + ((v.u >> 16) & 1u);
    return (unsigned short)(r >> 16);
}
__device__ __forceinline__ float bfhi(uint32_t u){ union{uint32_t u;float f;}v; v.u = u & 0xFFFF0000u; return v.f; }
__device__ __forceinline__ float bflo(uint32_t u){ union{uint32_t u;float f;}v; v.u = u << 16; return v.f; }
__device__ __forceinline__ float bf2f(short s){ union{uint32_t u;float f;}v; v.u = ((uint32_t)(unsigned short)s) << 16; return v.f; }

__device__ __forceinline__ float sigmoidf_(float x){
    float e = __expf(-x);
    return __builtin_amdgcn_rcpf(1.0f + e);
}
__device__ __forceinline__ float tanhf_(float x){
    float e = __expf(2.0f * x);
    return 1.0f - 2.0f * __builtin_amdgcn_rcpf(1.0f + e);
}

#define MFMA16(A, B, C) __builtin_amdgcn_mfma_f32_16x16x32_bf16((A), (B), (C), 0, 0, 0)

// ============================================================================
// Pack kernel: Wih1 (f32, row-major 512x128) -> bf16 fragment-ordered in d_ws.
// Fragment index F(wl,c,t) = (wl*4+c)*4+t ; lane l ; shorts at (F*64+l)*8.
// ============================================================================
__global__ __launch_bounds__(1024) void pack_wih1_kernel(
    const float* __restrict__ Wih1, short* __restrict__ dst)
{
    const int s2 = blockIdx.x * 1024 + threadIdx.x;   // 0..8191
    const int ll = s2 & 63;
    const int t  = (s2 >> 6) & 3;
    const int c  = (s2 >> 8) & 3;
    const int wl = s2 >> 10;
    const float* p = Wih1 + (t * 128 + wl * 16 + (ll & 15)) * HDIM + c * 32 + (ll >> 4) * 8;
    s16x8 a;
    #pragma unroll
    for (int j = 0; j < 8; ++j) a[j] = (short)f2bf(p[j]);
    *(s16x8*)&dst[s2 * 8] = a;
}

// ============================================================================
// Main: 128 blocks x 1024 threads (16 waves, 4/SIMD). Teams of 8 waves:
// L0 (w<8): Whh0 in regs (64), 16 units/wave.  L1 (w>=8): Whh1 from LDS,
// Wih1 from global (packed bf16 in ws), 16 units/wave. 1 barrier/step.
// ============================================================================
__global__ __launch_bounds__(1024, 4) void lstm_mega_kernel(
    const float* __restrict__ x,
    const float* __restrict__ Wih0,
    const float* __restrict__ Whh0,
    const float* __restrict__ bih0,
    const float* __restrict__ bhh0,
    const float* __restrict__ Whh1,
    const float* __restrict__ bih1,
    const float* __restrict__ bhh1,
    const float* __restrict__ W1,
    const float* __restrict__ b1,
    const float* __restrict__ W2,
    const float* __restrict__ b2,
    const short* __restrict__ wih1pk,   // packed bf16 fragments in ws
    float* __restrict__ out)
{
    __shared__ __align__(16) short whh1lds[65536];      // 128 KB
    __shared__ __align__(16) short h0f[2][2048];
    __shared__ __align__(16) short h1f[2][2048];
    __shared__ __align__(16) uint32_t b0wx[8][4][16];   // (wx<<16)|bias0, 2 KB
    __shared__ __align__(16) float    b1t[8][4][16];    // bias1, 2 KB

    const int tid = threadIdx.x;
    const int w   = tid >> 6;        // 0..15
    const int wl  = w & 7;           // wave-in-team; owns units [16wl,16wl+16)
    const bool isL0 = (w < 8);
    const int l = tid & 63;
    const int n = l & 15;            // batch col
    const int q = l >> 4;            // k-group / row-quad
    const int b0 = blockIdx.x * BT;
    const float* xrow = x + (size_t)(b0 + n) * TLEN;

    // ---- stage Whh1 into LDS fragment-ordered (8 frags per thread) ----
    #pragma unroll
    for (int i = 0; i < 8; ++i) {
        const int s2 = tid + i * 1024;
        const int ll = s2 & 63, t = (s2 >> 6) & 3, c = (s2 >> 8) & 3, wv = s2 >> 10;
        const float* p = Whh1 + (t * 128 + wv * 16 + (ll & 15)) * HDIM + c * 32 + (ll >> 4) * 8;
        s16x8 a;
        #pragma unroll
        for (int j = 0; j < 8; ++j) a[j] = (short)f2bf(p[j]);
        *(s16x8*)&whh1lds[s2 * 8] = a;
    }
    // ---- bias tables ----
    if (tid < 512) {
        const int wv = tid >> 6, t = (tid >> 4) & 3, j = tid & 15;
        const int row = t * 128 + wv * 16 + j;
        b0wx[wv][t][j] = ((uint32_t)f2bf(Wih0[row]) << 16) | f2bf(bih0[row] + bhh0[row]);
    } else {
        const int idx = tid - 512;
        const int wv = idx >> 6, t = (idx >> 4) & 3, j = idx & 15;
        const int row = t * 128 + wv * 16 + j;
        b1t[wv][t][j] = bih1[row] + bhh1[row];
    }
    // zero h1[-1] (read at k=0 from h1f[1]) : 1024 u32, one per thread
    ((uint32_t*)h1f[1])[tid] = 0u;

    // B-fragment write slot for this lane's 4 units
    const int u0 = wl * 16 + q * 4;
    const int fragoff = ((u0 >> 5) * 64 + n + 16 * ((u0 >> 3) & 3)) * 8 + (u0 & 7);

#define L0ITER(K, R, W) do {                                                  \
    const int xi_ = (K) + 1;                                                  \
    const float xv_ = xrow[xi_ < TLEN ? xi_ : (TLEN - 1)];                    \
    s16x8 hb_[4];                                                             \
    _Pragma("unroll")                                                         \
    for (int c = 0; c < 4; ++c) hb_[c] = *(const s16x8*)&(R)[(c * 64 + l) * 8]; \
    f32x4 acc_[4];                                                            \
    _Pragma("unroll")                                                         \
    for (int t = 0; t < 4; ++t) {                                             \
        const u32x4 bwt = *(const u32x4*)&b0wx[wl][t][q * 4];                 \
        _Pragma("unroll")                                                     \
        for (int r = 0; r < 4; ++r)                                           \
            acc_[t][r] = fmaf(bfhi(bwt[r]), xv_, bflo(bwt[r]));               \
    }                                                                         \
    _Pragma("unroll")                                                         \
    for (int c = 0; c < 4; ++c) {                                             \
        _Pragma("unroll")                                                     \
        for (int t = 0; t < 4; ++t)                                           \
            acc_[t] = MFMA16(w0f[c][t], hb_[c], acc_[t]);                     \
    }                                                                         \
    s16x4 hw_;                                                                \
    _Pragma("unroll")                                                         \
    for (int r = 0; r < 4; ++r) {                                             \
        const float ig = sigmoidf_(acc_[0][r]);                               \
        const float fg = sigmoidf_(acc_[1][r]);                               \
        const float gg = tanhf_(acc_[2][r]);                                  \
        const float og = sigmoidf_(acc_[3][r]);                               \
        const float cc = fmaf(fg, c0v[r], ig * gg);                           \
        c0v[r] = cc;                                                          \
        hw_[r] = (short)f2bf(og * tanhf_(cc));                                \
    }                                                                         \
    *(s16x4*)&(W)[fragoff] = hw_;                                             \
    __syncthreads();                                                          \
} while (0)

#define LOADWI(DST, C) do {                                                   \
    _Pragma("unroll")                                                         \
    for (int t4 = 0; t4 < 4; ++t4)                                            \
        (DST)[t4] = *(const s16x8*)&wih1pk[(((wl * 4 + (C)) * 4 + t4) * 64 + l) * 8]; \
} while (0)

#define L1ITER(K, R0, R1, W1B) do {                                           \
    s16x8 wiA_[4], wiB_[4];                                                   \
    LOADWI(wiA_, 0); LOADWI(wiB_, 1);                                         \
    s16x8 hb0_[4], hb1_[4];                                                   \
    _Pragma("unroll")                                                         \
    for (int c = 0; c < 4; ++c) {                                             \
        hb0_[c] = *(const s16x8*)&(R0)[(c * 64 + l) * 8];                     \
        hb1_[c] = *(const s16x8*)&(R1)[(c * 64 + l) * 8];                     \
    }                                                                         \
    f32x4 acc_[4];                                                            \
    _Pragma("unroll")                                                         \
    for (int t = 0; t < 4; ++t) acc_[t] = *(const f32x4*)&b1t[wl][t][q * 4];  \
    _Pragma("unroll")                                                         \
    for (int c = 0; c < 4; ++c) {                                             \
        s16x8 wt_[4];                                                         \
        _Pragma("unroll")                                                     \
        for (int t = 0; t < 4; ++t)                                           \
            wt_[t] = *(const s16x8*)&whh1lds[(((wl * 4 + c) * 4 + t) * 64 + l) * 8]; \
        _Pragma("unroll")                                                     \
        for (int t = 0; t < 4; ++t)                                           \
            acc_[t] = MFMA16(wt_[t], hb1_[c], acc_[t]);                       \
    }                                                                         \
    _Pragma("unroll")                                                         \
    for (int t = 0; t < 4; ++t) acc_[t] = MFMA16(wiA_[t], hb0_[0], acc_[t]);  \
    LOADWI(wiA_, 2);                                                          \
    _Pragma("unroll")                                                         \
    for (int t = 0; t < 4; ++t) acc_[t] = MFMA16(wiB_[t], hb0_[1], acc_[t]);  \
    LOADWI(wiB_, 3);                                                          \
    _Pragma("unroll")                                                         \
    for (int t = 0; t < 4; ++t) acc_[t] = MFMA16(wiA_[t], hb0_[2], acc_[t]);  \
    _Pragma("unroll")                                                         \
    for (int t = 0; t < 4; ++t) acc_[t] = MFMA16(wiB_[t], hb0_[3], acc_[t]);  \
    s16x4 hw_;                                                                \
    _Pragma("unroll")                                                         \
    for (int r = 0; r < 4; ++r) {                                             \
        const float ig = sigmoidf_(acc_[0][r]);                               \
        const float fg = sigmoidf_(acc_[1][r]);                               \
        const float gg = tanhf_(acc_[2][r]);                                  \
        const float og = sigmoidf_(acc_[3][r]);                               \
        const float cc = fmaf(fg, c1v[r], ig * gg);                           \
        c1v[r] = cc;                                                          \
        hw_[r] = (short)f2bf(og * tanhf_(cc));                                \
    }                                                                         \
    *(s16x4*)&(W1B)[fragoff] = hw_;                                           \
    __syncthreads();                                                          \
} while (0)

    if (isL0) {
        // ---- L0 wave: Whh0 fragments for its 16 units (64 VGPRs) ----
        s16x8 w0f[4][4];   // [c][t]
        #pragma unroll
        for (int c = 0; c < 4; ++c) {
            #pragma unroll
            for (int t = 0; t < 4; ++t) {
                const float* p = Whh0 + (t * 128 + wl * 16 + n) * HDIM + c * 32 + q * 8;
                s16x8 a;
                #pragma unroll
                for (int j = 0; j < 8; ++j) a[j] = (short)f2bf(p[j]);
                w0f[c][t] = a;
            }
        }
        float c0v[4] = {0.f, 0.f, 0.f, 0.f};

        __syncthreads();   // staging (b0wx, whh1lds, h1f[1]) visible

        // prologue: h0[0] = pointwise(b0 + wx*x[0]) ; h0[-1]=0 so no MFMA
        {
            const float x0 = xrow[0];
            u32x4 bw0 = *(const u32x4*)&b0wx[wl][0][q * 4];
            u32x4 bw2 = *(const u32x4*)&b0wx[wl][2][q * 4];
            u32x4 bw3 = *(const u32x4*)&b0wx[wl][3][q * 4];
            s16x4 hw;
            #pragma unroll
            for (int r = 0; r < 4; ++r) {
                const float pi = fmaf(bfhi(bw0[r]), x0, bflo(bw0[r]));
                const float pg = fmaf(bfhi(bw2[r]), x0, bflo(bw2[r]));
                const float po = fmaf(bfhi(bw3[r]), x0, bflo(bw3[r]));
                const float ig = sigmoidf_(pi);
                const float gg = tanhf_(pg);
                const float og = sigmoidf_(po);
                const float cc = ig * gg;          // f * c(-1) = 0
                c0v[r] = cc;
                hw[r] = (short)f2bf(og * tanhf_(cc));
            }
            *(s16x4*)&h0f[0][fragoff] = hw;
        }
        __syncthreads();   // h0[0] visible

        #pragma unroll 1
        for (int k = 0; k < TLEN; k += 2) {
            L0ITER(k,     h0f[0], h0f[1]);
            L0ITER(k + 1, h0f[1], h0f[0]);
        }
    } else {
        float c1v[4] = {0.f, 0.f, 0.f, 0.f};
        __syncthreads();   // pairs with L0 post-staging barrier
        __syncthreads();   // pairs with L0 post-prologue barrier

        #pragma unroll 1
        for (int k = 0; k < TLEN; k += 2) {
            L1ITER(k,     h0f[0], h1f[1], h1f[0]);
            L1ITER(k + 1, h0f[1], h1f[0], h1f[1]);
        }
        // h1[511] now in h1f[1]
    }

    // ---- head: aliases whh1lds (all weight reads are behind the last barrier) ----
    float* headH = (float*)whh1lds;          // [16][128] f32 = 8 KB
    float* headL = headH + 16 * HDIM;        // [16][64]  = 4 KB
    if (!isL0) {
        const s16x4 hv = *(const s16x4*)&h1f[1][fragoff];
        f32x4 hf;
        #pragma unroll
        for (int r = 0; r < 4; ++r) hf[r] = bf2f(hv[r]);
        *(f32x4*)&headH[n * HDIM + u0] = hf;
    }
    __syncthreads();

    {   // hidden = relu(h @ W1^T + b1): 1024 threads = 16 batch x 64 hidden
        const int nn = tid >> 6, j = tid & 63;
        float s = b1[j];
        const float* wrow = W1 + j * HDIM;
        const float* hrow = headH + nn * HDIM;
        #pragma unroll
        for (int k = 0; k < HDIM; k += 4) {
            const f32x4 hv = *(const f32x4*)&hrow[k];
            const f32x4 wv = *(const f32x4*)&wrow[k];
            s += hv[0]*wv[0] + hv[1]*wv[1] + hv[2]*wv[2] + hv[3]*wv[3];
        }
        headL[nn * 64 + j] = fmaxf(s, 0.0f);
    }
    __syncthreads();

    if (tid < 128) {
        const int nn = tid >> 3, cls = tid & 7;
        float s = b2[cls];
        const float* wrow = W2 + cls * 64;
        const float* hrow = headL + nn * 64;
        #pragma unroll
        for (int k = 0; k < 64; k += 4) {
            const f32x4 hv = *(const f32x4*)&hrow[k];
            const f32x4 wv = *(const f32x4*)&wrow[k];
            s += hv[0]*wv[0] + hv[1]*wv[1] + hv[2]*wv[2] + hv[3]*wv[3];
        }
        out[(size_t)(b0 + nn) * 8 + cls] = s;
    }
#undef L0ITER
#undef LOADWI
#undef L1ITER
}

// ============================================================================
// Fallback (round-6 kernel, 954 us): used when ws_size < 128 KB.
// ============================================================================
__global__ __launch_bounds__(512, 2) void lstm_fused_kernel(
    const float* __restrict__ x,
    const float* __restrict__ Wih0,
    const float* __restrict__ Whh0,
    const float* __restrict__ bih0,
    const float* __restrict__ bhh0,
    const float* __restrict__ Wih1,
    const float* __restrict__ Whh1,
    const float* __restrict__ bih1,
    const float* __restrict__ bhh1,
    const float* __restrict__ W1,
    const float* __restrict__ b1,
    const float* __restrict__ W2,
    const float* __restrict__ b2,
    float* __restrict__ out)
{
    __shared__ __align__(16) short wh1lds[65536];
    __shared__ __align__(16) short h0f0[2048], h0f1[2048];
    __shared__ __align__(16) short h1f0[2048], h1f1[2048];
    __shared__ __align__(16) float b1lds[4][8][16];

    const int tid = threadIdx.x;
    const int w   = tid >> 6;
    const int wl  = w & 3;
    const bool isL0 = (w < 4);
    const int l = tid & 63;
    const int n = l & 15;
    const int q = l >> 4;
    const int b0 = blockIdx.x * BT;
    const float* xrow = x + (size_t)(b0 + n) * TLEN;

    for (int s2 = tid; s2 < 8192; s2 += 512) {
        const int ll = s2 & 63, t2 = (s2 >> 6) & 7, cc = (s2 >> 9) & 3, wv = s2 >> 11;
        const int row = (t2 >> 1) * 128 + 32 * wv + 16 * (t2 & 1) + (ll & 15);
        const int k0  = cc * 32 + (ll >> 4) * 8;
        const float* p = Whh1 + row * HDIM + k0;
        s16x8 a;
        #pragma unroll
        for (int j = 0; j < 8; ++j) a[j] = (short)f2bf(p[j]);
        *(s16x8*)&wh1lds[s2 * 8] = a;
    }
    {
        const int idx = tid;
        const int wv = idx >> 7, t2 = (idx >> 4) & 7, j = idx & 15;
        const int row = (t2 >> 1) * 128 + 32 * wv + 16 * (t2 & 1) + j;
        b1lds[wv][t2][j] = bih1[row] + bhh1[row];
    }
    for (int s2 = tid; s2 < 1024; s2 += 512) ((uint32_t*)h1f1)[s2] = 0u;

    const int ub0 = 32 * wl + 4 * q;
    const int ub1 = ub0 + 16;
    const int fo0 = ((ub0 >> 5) * 64 + n + 16 * ((ub0 >> 3) & 3)) * 8 + (ub0 & 7);
    const int fo1 = ((ub1 >> 5) * 64 + n + 16 * ((ub1 >> 3) & 3)) * 8 + (ub1 & 7);

#define L0ITER(K, R0, W0) do {                                                \
    const int xi_ = (K) + 1;                                                  \
    const float xv_ = xrow[xi_ < TLEN ? xi_ : (TLEN - 1)];                    \
    s16x8 hb_[4];                                                             \
    _Pragma("unroll")                                                         \
    for (int c = 0; c < 4; ++c) hb_[c] = *(const s16x8*)&(R0)[(c * 64 + l) * 8]; \
    f32x4 a_[8];                                                              \
    _Pragma("unroll")                                                         \
    for (int t2 = 0; t2 < 8; ++t2) {                                          \
        _Pragma("unroll")                                                     \
        for (int r = 0; r < 4; ++r)                                           \
            a_[t2][r] = fmaf(bfhi(bwx[t2][r]), xv_, bflo(bwx[t2][r]));        \
    }                                                                         \
    _Pragma("unroll")                                                         \
    for (int c = 0; c < 4; ++c) {                                             \
        _Pragma("unroll")                                                     \
        for (int t2 = 0; t2 < 8; ++t2)                                        \
            a_[t2] = MFMA16(w0f[c][t2], hb_[c], a_[t2]);                      \
    }                                                                         \
    _Pragma("unroll")                                                         \
    for (int h = 0; h < 2; ++h) {                                             \
        s16x4 hw;                                                             \
        _Pragma("unroll")                                                     \
        for (int r = 0; r < 4; ++r) {                                         \
            const float ig = sigmoidf_(a_[0 + h][r]);                         \
            const float fg = sigmoidf_(a_[2 + h][r]);                         \
            const float gg = tanhf_(a_[4 + h][r]);                            \
            const float og = sigmoidf_(a_[6 + h][r]);                         \
            const float cc = fmaf(fg, c0_[h][r], ig * gg);                    \
            c0_[h][r] = cc;                                                   \
            hw[r] = (short)f2bf(og * tanhf_(cc));                             \
        }                                                                     \
        *(s16x4*)&(W0)[h ? fo1 : fo0] = hw;                                   \
    }                                                                         \
    __syncthreads();                                                          \
} while (0)

#define L1ITER(K, R0, R1, W1) do {                                            \
    s16x8 hb0_[4], hb1_[4];                                                   \
    _Pragma("unroll")                                                         \
    for (int c = 0; c < 4; ++c) {                                             \
        hb0_[c] = *(const s16x8*)&(R0)[(c * 64 + l) * 8];                     \
        hb1_[c] = *(const s16x8*)&(R1)[(c * 64 + l) * 8];                     \
    }                                                                         \
    f32x4 a_[8];                                                              \
    _Pragma("unroll")                                                         \
    for (int t2 = 0; t2 < 8; ++t2)                                            \
        a_[t2] = *(const f32x4*)&b1lds[wl][t2][q * 4];                        \
    _Pragma("unroll")                                                         \
    for (int c = 0; c < 4; ++c) {                                             \
        _Pragma("unroll")                                                     \
        for (int t2 = 0; t2 < 8; ++t2)                                        \
            a_[t2] = MFMA16(wi1f[c][t2], hb0_[c], a_[t2]);                    \
    }                                                                         \
    _Pragma("unroll")                                                         \
    for (int c = 0; c < 4; ++c) {                                             \
        s16x8 wt_[8];                                                         \
        _Pragma("unroll")                                                     \
        for (int t2 = 0; t2 < 8; ++t2)                                        \
            wt_[t2] = *(const s16x8*)&wh1lds[(((wl * 4 + c) * 8 + t2) * 64 + l) * 8]; \
        _Pragma("unroll")                                                     \
        for (int t2 = 0; t2 < 8; ++t2)                                        \
            a_[t2] = MFMA16(wt_[t2], hb1_[c], a_[t2]);                        \
    }                                                                         \
    _Pragma("unroll")                                                         \
    for (int h = 0; h < 2; ++h) {                                             \
        s16x4 hw;                                                             \
        _Pragma("unroll")                                                     \
        for (int r = 0; r < 4; ++r) {                                         \
            const float ig = sigmoidf_(a_[0 + h][r]);                         \
            const float fg = sigmoidf_(a_[2 + h][r]);                         \
            const float gg = tanhf_(a_[4 + h][r]);                            \
            const float og = sigmoidf_(a_[6 + h][r]);                         \
            const float cc = fmaf(fg, c1_[h][r], ig * gg);                    \
            c1_[h][r] = cc;                                                   \
            hw[r] = (short)f2bf(og * tanhf_(cc));                             \
        }                                                                     \
        *(s16x4*)&(W1)[h ? fo1 : fo0] = hw;                                   \
    }                                                                         \
    __syncthreads();                                                          \
} while (0)

    if (isL0) {
        s16x8 w0f[4][8];
        #pragma unroll
        for (int c = 0; c < 4; ++c) {
            #pragma unroll
            for (int t2 = 0; t2 < 8; ++t2) {
                const int row = (t2 >> 1) * 128 + 32 * wl + 16 * (t2 & 1) + n;
                const int k0 = c * 32 + q * 8;
                const float* p = Whh0 + row * HDIM + k0;
                s16x8 a;
                #pragma unroll
                for (int j = 0; j < 8; ++j) a[j] = (short)f2bf(p[j]);
                w0f[c][t2] = a;
            }
        }
        u32x4 bwx[8];
        #pragma unroll
        for (int t2 = 0; t2 < 8; ++t2) {
            #pragma unroll
            for (int r = 0; r < 4; ++r) {
                const int row = (t2 >> 1) * 128 + 32 * wl + 16 * (t2 & 1) + 4 * q + r;
                bwx[t2][r] = ((uint32_t)f2bf(Wih0[row]) << 16) | f2bf(bih0[row] + bhh0[row]);
            }
        }
        float c0_[2][4] = {{0.f,0.f,0.f,0.f},{0.f,0.f,0.f,0.f}};
        {
            const float x0 = xrow[0];
            #pragma unroll
            for (int h = 0; h < 2; ++h) {
                s16x4 hw;
                #pragma unroll
                for (int r = 0; r < 4; ++r) {
                    const float pi = fmaf(bfhi(bwx[0 + h][r]), x0, bflo(bwx[0 + h][r]));
                    const float pg = fmaf(bfhi(bwx[4 + h][r]), x0, bflo(bwx[4 + h][r]));
                    const float po = fmaf(bfhi(bwx[6 + h][r]), x0, bflo(bwx[6 + h][r]));
                    const float ig = sigmoidf_(pi);
                    const float gg = tanhf_(pg);
                    const float og = sigmoidf_(po);
                    const float cc = ig * gg;
                    c0_[h][r] = cc;
                    hw[r] = (short)f2bf(og * tanhf_(cc));
                }
                *(s16x4*)&h0f0[h ? fo1 : fo0] = hw;
            }
        }
        __syncthreads();
        #pragma unroll 1
        for (int k = 0; k < TLEN; k += 2) {
            L0ITER(k,     h0f0, h0f1);
            L0ITER(k + 1, h0f1, h0f0);
        }
    } else {
        s16x8 wi1f[4][8];
        #pragma unroll
        for (int c = 0; c < 4; ++c) {
            #pragma unroll
            for (int t2 = 0; t2 < 8; ++t2) {
                const int row = (t2 >> 1) * 128 + 32 * wl + 16 * (t2 & 1) + n;
                const int k0 = c * 32 + q * 8;
                const float* p = Wih1 + row * HDIM + k0;
                s16x8 a;
                #pragma unroll
                for (int j = 0; j < 8; ++j) a[j] = (short)f2bf(p[j]);
                wi1f[c][t2] = a;
            }
        }
        float c1_[2][4] = {{0.f,0.f,0.f,0.f},{0.f,0.f,0.f,0.f}};
        __syncthreads();
        #pragma unroll 1
        for (int k = 0; k < TLEN; k += 2) {
            L1ITER(k,     h0f0, h1f1, h1f0);
            L1ITER(k + 1, h0f1, h1f0, h1f1);
        }
    }

    __syncthreads();

    float* headH = (float*)wh1lds;
    float* headL = headH + 16 * HDIM;
    if (!isL0) {
        #pragma unroll
        for (int h = 0; h < 2; ++h) {
            const s16x4 hv = *(const s16x4*)&h1f1[h ? fo1 : fo0];
            f32x4 hf;
            #pragma unroll
            for (int r = 0; r < 4; ++r) hf[r] = bf2f(hv[r]);
            *(f32x4*)&headH[n * HDIM + (h ? ub1 : ub0)] = hf;
        }
    }
    __syncthreads();

    #pragma unroll
    for (int rep = 0; rep < 2; ++rep) {
        const int idx = tid + rep * 512;
        const int nn = idx >> 6, j = idx & 63;
        float s = b1[j];
        const float* wrow = W1 + j * HDIM;
        const float* hrow = headH + nn * HDIM;
        #pragma unroll
        for (int k = 0; k < HDIM; k += 4) {
            const f32x4 hv = *(const f32x4*)&hrow[k];
            const f32x4 wv = *(const f32x4*)&wrow[k];
            s += hv[0]*wv[0] + hv[1]*wv[1] + hv[2]*wv[2] + hv[3]*wv[3];
        }
        headL[nn * 64 + j] = fmaxf(s, 0.0f);
    }
    __syncthreads();

    if (tid < 128) {
        const int nn = tid >> 3, cls = tid & 7;
        float s = b2[cls];
        const float* wrow = W2 + cls * 64;
        const float* hrow = headL + nn * 64;
        #pragma unroll
        for (int k = 0; k < 64; k += 4) {
            const f32x4 hv = *(const f32x4*)&hrow[k];
            const f32x4 wv = *(const f32x4*)&wrow[k];
            s += hv[0]*wv[0] + hv[1]*wv[1] + hv[2]*wv[2] + hv[3]*wv[3];
        }
        out[(size_t)(b0 + nn) * 8 + cls] = s;
    }
#undef L0ITER
#undef L1ITER
}

extern "C" void kernel_launch(void* const* d_in, const int* in_sizes, int n_in,
                              void* d_out, int out_size, void* d_ws, size_t ws_size,
                              hipStream_t stream) {
    const float* x    = (const float*)d_in[0];
    const float* Wih0 = (const float*)d_in[1];
    const float* Whh0 = (const float*)d_in[2];
    const float* bih0 = (const float*)d_in[3];
    const float* bhh0 = (const float*)d_in[4];
    const float* Wih1 = (const float*)d_in[5];
    const float* Whh1 = (const float*)d_in[6];
    const float* bih1 = (const float*)d_in[7];
    const float* bhh1 = (const float*)d_in[8];
    const float* W1   = (const float*)d_in[9];
    const float* b1   = (const float*)d_in[10];
    const float* W2   = (const float*)d_in[11];
    const float* b2   = (const float*)d_in[12];
    float* outp = (float*)d_out;

    const size_t PACK_BYTES = (size_t)512 * 128 * sizeof(short);   // 128 KB

    if (ws_size >= PACK_BYTES) {
        short* wih1pk = (short*)d_ws;
        pack_wih1_kernel<<<8, 1024, 0, stream>>>(Wih1, wih1pk);
        lstm_mega_kernel<<<128, 1024, 0, stream>>>(
            x, Wih0, Whh0, bih0, bhh0, Whh1, bih1, bhh1,
            W1, b1, W2, b2, wih1pk, outp);
    } else {
        lstm_fused_kernel<<<128, 512, 0, stream>>>(
            x, Wih0, Whh0, bih0, bhh0, Wih1, Whh1, bih1, bhh1,
            W1, b1, W2, b2, outp);
    }
}